// Round 10
// baseline (524.321 us; speedup 1.0000x reference)
//
#include <hip/hip_runtime.h>

typedef unsigned short ushort_t;
typedef __attribute__((ext_vector_type(8))) short bf16x8;
typedef __attribute__((ext_vector_type(4))) float f32x4;

#define DEV static __device__ __forceinline__

DEV ushort_t f2bf(float f){
  union { float f; unsigned u; } v; v.f = f;
  unsigned r = v.u + 0x7FFFu + ((v.u >> 16) & 1u);
  return (ushort_t)(r >> 16);
}
DEV float bf2f(ushort_t h){
  union { unsigned u; float f; } v; v.u = ((unsigned)h) << 16;
  return v.f;
}
DEV float gelu_f(float x){ return 0.5f * x * (1.f + erff(x * 0.70710678118654752f)); }

#define MFMA16(a,b,c) __builtin_amdgcn_mfma_f32_16x16x32_bf16((a),(b),(c),0,0,0)

DEV void gld16(const ushort_t* g, ushort_t* l){
  __builtin_amdgcn_global_load_lds(
      (const __attribute__((address_space(1))) unsigned int*)g,
      (__attribute__((address_space(3))) unsigned int*)l, 16, 0, 0);
}

// ---------------- fused weight prep ----------------

__global__ __launch_bounds__(256) void transpose_all_kernel(
    const float* __restrict__ s0, const float* __restrict__ s1,
    const float* __restrict__ s2, const float* __restrict__ s3,
    ushort_t* __restrict__ d0, ushort_t* __restrict__ d1,
    ushort_t* __restrict__ d2, ushort_t* __restrict__ d3){
  __shared__ float tile[32][33];
  int b = blockIdx.x;
  const float* src; ushort_t* dst; int K, N, bx, by;
  if(b < 1728){ src=s0; dst=d0; K=768;  N=2304; bx=b%24;          by=b/24; }
  else if(b < 2304){ int c=b-1728; src=s1; dst=d1; K=768;  N=768;  bx=c%24; by=c/24; }
  else if(b < 4608){ int c=b-2304; src=s2; dst=d2; K=768;  N=3072; bx=c%24; by=c/24; }
  else             { int c=b-4608; src=s3; dst=d3; K=3072; N=768;  bx=c%96; by=c/96; }
  int k0 = bx*32, n0 = by*32;
  int tx = threadIdx.x & 31, ty = threadIdx.x >> 5;
  #pragma unroll
  for(int i = ty; i < 32; i += 8) tile[i][tx] = src[(long)(k0+i)*N + n0 + tx];
  __syncthreads();
  #pragma unroll
  for(int i = ty; i < 32; i += 8) dst[(long)(n0+i)*K + k0 + tx] = f2bf(tile[tx][i]);
}

__global__ void cast_all_kernel(
    const float* __restrict__ c1w, const float* __restrict__ c2w,
    const float* __restrict__ c3w, const float* __restrict__ rph,
    const float* __restrict__ rpw,
    ushort_t* __restrict__ wc1, ushort_t* __restrict__ wc2,
    ushort_t* __restrict__ wc3, ushort_t* __restrict__ tabh,
    ushort_t* __restrict__ tabw){
  int i = blockIdx.x*256 + threadIdx.x;
  if(i < 294912){ wc1[i] = f2bf(c1w[i]); }
  else if(i < 1622016){
    int j = i - 294912;
    int co = j / 3456, r = j - co*3456;
    int dy = r / 1152; int r2 = r - dy*1152;
    int dx = r2 / 384; int ci = r2 - dx*384;
    wc2[j] = f2bf(c2w[((co*384 + ci)*3 + dy)*3 + dx]);
  }
  else if(i < 1916928){ int j = i - 1622016; wc3[j] = f2bf(c3w[j]); }
  else if(i < 1923008){ int j = i - 1916928; tabh[j] = f2bf(rph[j]); }
  else if(i < 1929088){ int j = i - 1923008; tabw[j] = f2bf(rpw[j]); }
}

// V [bh][n][64] -> VT [bh][64][n]
__global__ __launch_bounds__(256) void vt_kernel(
    const ushort_t* __restrict__ v, ushort_t* __restrict__ vt){
  __shared__ __align__(16) ushort_t t[64][72];
  int bh = blockIdx.y, nt = blockIdx.x;
  int tid = threadIdx.x;
  #pragma unroll
  for(int p=0;p<2;p++){
    int item = tid + p*256;
    int tok = item >> 3, ch = item & 7;
    bf16x8 vv = *(const bf16x8*)(v + ((long)(bh*2304 + nt*64 + tok))*64 + ch*8);
    #pragma unroll
    for(int j=0;j<8;j++) t[ch*8+j][tok] = (ushort_t)vv[j];
  }
  __syncthreads();
  #pragma unroll
  for(int p=0;p<2;p++){
    int item = tid + p*256;
    int d = item >> 3, c2 = item & 7;
    bf16x8 rd = *(const bf16x8*)&t[d][c2*8];
    *(bf16x8*)(vt + ((long)(bh*64 + d))*2304 + nt*64 + c2*8) = rd;
  }
}

// ---------------- LayerNorm ----------------
template<int D, bool GELU, bool RES, bool PADOUT>
__global__ __launch_bounds__(256) void ln_kernel(
    const float* __restrict__ in, const float* __restrict__ w, const float* __restrict__ bv,
    const float* __restrict__ res, float eps,
    ushort_t* __restrict__ outb, float* __restrict__ outf){
  constexpr int PER = D/64;
  int lane = threadIdx.x & 63, wid = threadIdx.x >> 6;
  long row = (long)blockIdx.x*4 + wid;
  const float* ip = in + row*D;
  float x[PER]; float s = 0.f;
  #pragma unroll
  for(int i=0;i<PER;i++){ x[i] = ip[i*64 + lane]; s += x[i]; }
  #pragma unroll
  for(int o=32;o>=1;o>>=1) s += __shfl_xor(s, o);
  float mu = s * (1.f/D);
  float vs = 0.f;
  #pragma unroll
  for(int i=0;i<PER;i++){ float d = x[i]-mu; vs += d*d; }
  #pragma unroll
  for(int o=32;o>=1;o>>=1) vs += __shfl_xor(vs, o);
  float rstd = rsqrtf(vs*(1.f/D) + eps);
  long obase;
  if constexpr(PADOUT){
    int bb = (int)(row / 2304); int rm = (int)(row - (long)bb*2304);
    int y = rm / 48, xx = rm - y*48;
    obase = ((long)((bb*50 + y+1)*50) + (xx+1))*384;
  } else obase = row*D;
  #pragma unroll
  for(int i=0;i<PER;i++){
    int c = i*64 + lane;
    float y = (x[i]-mu)*rstd*w[c] + bv[c];
    if constexpr(GELU) y = gelu_f(y);
    if constexpr(RES)  y += res[row*D + c];
    if(outb) outb[obase + c] = f2bf(y);
    if(outf) outf[row*D + c] = y;
  }
}

// ---------------- rel-pos bias tables via MFMA ----------------
__global__ __launch_bounds__(256) void relpos_mfma_kernel(
    const ushort_t* __restrict__ q, const ushort_t* __restrict__ tabh,
    const ushort_t* __restrict__ tabw,
    float* __restrict__ relh, float* __restrict__ relw){
  const int bh = blockIdx.y;
  const bool isH = (blockIdx.z == 0);
  const int w = threadIdx.x >> 6, lane = threadIdx.x & 63;
  const int la = lane & 15, grp = lane >> 4;
  const int pos0 = blockIdx.x*4 + w;
  const ushort_t* tab = isH ? tabh : tabw;
  float* outp = isH ? relh : relw;
  const ushort_t* qbase = q + (long)bh*2304*64;

  bf16x8 bf0[3], bf1[3];
  #pragma unroll
  for(int ni=0;ni<3;ni++){
    int dpos = pos0 - (ni*16+la) + 47;
    const ushort_t* tp = tab + dpos*64 + grp*8;
    bf0[ni] = *(const bf16x8*)tp;
    bf1[ni] = *(const bf16x8*)(tp+32);
  }
  #pragma unroll
  for(int mi=0;mi<3;mi++){
    int arow = mi*16 + la;
    long na = isH ? ((long)pos0*48 + arow) : ((long)arow*48 + pos0);
    const ushort_t* qp = qbase + na*64 + grp*8;
    bf16x8 a0 = *(const bf16x8*)qp;
    bf16x8 a1 = *(const bf16x8*)(qp+32);
    f32x4 c[3];
    #pragma unroll
    for(int ni=0;ni<3;ni++){
      f32x4 z; z[0]=0.f; z[1]=0.f; z[2]=0.f; z[3]=0.f;
      z = MFMA16(a0, bf0[ni], z);
      z = MFMA16(a1, bf1[ni], z);
      c[ni] = z;
    }
    #pragma unroll
    for(int ni=0;ni<3;ni++)
      #pragma unroll
      for(int r=0;r<4;r++){
        int orow = mi*16 + grp*4 + r;
        long no = isH ? ((long)pos0*48 + orow) : ((long)orow*48 + pos0);
        outp[((long)bh*2304 + no)*48 + ni*16 + la] = c[ni][r] * 8.0f;
      }
  }
}

// ---------------- MFMA GEMM, BM x BN tile, gld16 + XOR-swizzle ----------------
template<int BM, int BN, int EPI, bool IM2COL>
__global__ __launch_bounds__(256) void gemm_kernel(
    const ushort_t* __restrict__ A, const ushort_t* __restrict__ Wt,
    const float* __restrict__ bias, const float* __restrict__ res,
    float* __restrict__ outf, ushort_t* __restrict__ ob0,
    ushort_t* __restrict__ ob1, ushort_t* __restrict__ ob2,
    int N, int Kdim){
  constexpr int FRm = BM/32, FRn = BN/32;
  __shared__ __align__(16) ushort_t Asm[BM*64];
  __shared__ __align__(16) ushort_t Bsm[BN*64];
  const int tid = threadIdx.x, lane = tid & 63, w = tid >> 6;
  const int wm = w >> 1, wn = w & 1;
  const int la = lane & 15, grp = lane >> 4;
  const int m0 = blockIdx.y * BM, n0 = blockIdx.x * BN;
  f32x4 acc[FRm][FRn];
  #pragma unroll
  for(int i=0;i<FRm;i++)
    #pragma unroll
    for(int j=0;j<FRn;j++)
      #pragma unroll
      for(int r=0;r<4;r++) acc[i][j][r] = 0.f;

  const int srw = lane >> 3;
  const int scs = ((lane&7) ^ srw) * 8;
  for(int k0 = 0; k0 < Kdim; k0 += 64){
    if(k0) __syncthreads();
    #pragma unroll
    for(int t=0;t<FRm;t++){
      int r = w*(BM/4) + t*8 + srw;
      const ushort_t* ga;
      if constexpr(IM2COL){
        int m = m0 + r;
        int bb = m / 2304; int rm = m - bb*2304;
        int y = rm / 48, x = rm - y*48;
        int dy = k0 / 1152; int r2 = k0 - dy*1152;
        int dx = r2 / 384;  int cb = r2 - dx*384;
        ga = A + (((long)((bb*50 + y+dy)*50) + (x+dx))*384 + cb + scs);
      } else {
        ga = A + (long)(m0+r)*Kdim + k0 + scs;
      }
      gld16(ga, &Asm[(w*(BM/4)+t*8)*64]);
    }
    #pragma unroll
    for(int t=0;t<FRn;t++){
      int r = w*(BN/4) + t*8 + srw;
      gld16(Wt + (long)(n0+r)*Kdim + k0 + scs, &Bsm[(w*(BN/4)+t*8)*64]);
    }
    __syncthreads();
    #pragma unroll
    for(int ks=0; ks<2; ks++){
      bf16x8 af[FRm], bfm[FRn];
      #pragma unroll
      for(int mi=0;mi<FRm;mi++){
        int row = wm*(BM/2) + mi*16 + la;
        af[mi] = *(const bf16x8*)&Asm[row*64 + ((((ks<<2)+grp) ^ (row&7))*8)];
      }
      #pragma unroll
      for(int ni=0;ni<FRn;ni++){
        int row = wn*(BN/2) + ni*16 + la;
        bfm[ni] = *(const bf16x8*)&Bsm[row*64 + ((((ks<<2)+grp) ^ (row&7))*8)];
      }
      #pragma unroll
      for(int mi=0;mi<FRm;mi++)
        #pragma unroll
        for(int ni=0;ni<FRn;ni++)
          acc[mi][ni] = MFMA16(af[mi], bfm[ni], acc[mi][ni]);
    }
  }
  #pragma unroll
  for(int mi=0;mi<FRm;mi++)
  #pragma unroll
  for(int ni=0;ni<FRn;ni++)
  #pragma unroll
  for(int r=0;r<4;r++){
    int mm = m0 + wm*(BM/2) + mi*16 + grp*4 + r;
    int nn = n0 + wn*(BN/2) + ni*16 + la;
    float v = acc[mi][ni][r];
    if constexpr(EPI == 0){
      outf[(long)mm*N + nn] = v;
    } else if constexpr(EPI == 1){
      v += bias[nn];
      int s = nn / 768; int rem = nn - s*768;
      int head = rem >> 6, d = rem & 63;
      if(s == 0) v *= 0.125f;
      int bb = mm / 2304; int nloc = mm - bb*2304;
      long idx = ((long)((bb*12+head)*2304 + nloc))*64 + d;
      ushort_t hv = f2bf(v);
      if(s == 0) ob0[idx] = hv; else if(s == 1) ob1[idx] = hv; else ob2[idx] = hv;
    } else if constexpr(EPI == 2){
      v += bias[nn] + res[(long)mm*N + nn];
      outf[(long)mm*N + nn] = v;
    } else if constexpr(EPI == 3){
      v = gelu_f(v + bias[nn]);
      ob0[(long)mm*N + nn] = f2bf(v);
    } else if constexpr(EPI == 4){
      v += bias[nn] + res[(long)mm*N + nn];
      outf[(long)mm*N + nn] = v;
      ob0[(long)mm*N + nn] = f2bf(v);
    }
  }
}

// ---------------- flash attention: 8 waves x 16q, K via LDS 2-phase, V direct from L2 ----------------
// grid (18 qt, 24 bh, 2 sp), 512 threads. Wave w owns q rows qt*128+w*16+la.
// Per iter: vmcnt(0) -> s_barrier -> V-loads (global) -> rh loads -> K-DMA(j+1) -> QK^T -> softmax -> PV.
// Issue order keeps K prefetch outstanding across the compiler's pre-PV waitcnt (T4).
#define NSPLIT 2
#define NTS 18
__global__ __launch_bounds__(512) void attn_kernel(
    const ushort_t* __restrict__ Q, const ushort_t* __restrict__ Kb,
    const ushort_t* __restrict__ VT, const float* __restrict__ relh,
    const float* __restrict__ relw, float* __restrict__ Opart,
    float* __restrict__ mpart, float* __restrict__ lpart){
  __shared__ __align__(16) ushort_t Kl[2][64*64];
  const int bh = blockIdx.y, qt = blockIdx.x, sp = blockIdx.z;
  const int tid = threadIdx.x, lane = tid & 63, w = tid >> 6;   // w 0..7
  const int la = lane & 15, grp = lane >> 4;
  const int qg = qt*128 + w*16 + la;
  const long row = (long)bh*2304 + qg;
  const int key0 = sp*NTS*64;

  const ushort_t* qp = Q + row*64 + grp*8;
  const bf16x8 qa0 = *(const bf16x8*)qp;
  const bf16x8 qa1 = *(const bf16x8*)(qp + 32);

  const ushort_t* kg = Kb + ((long)bh*2304 + key0)*64;
  const ushort_t* vg = VT + (long)bh*64*2304 + key0;
  const float* rhq = relh + row*48;

  f32x4 rw4[3];
  {
    const float* rwq = relw + row*48 + grp*4;
    #pragma unroll
    for(int c=0;c<3;c++) rw4[c] = *(const f32x4*)(rwq + 16*c);
  }

  const int srw = lane >> 3;
  const int scs = ((lane&7) ^ srw) * 8;
  const int strow = w*8 + srw;

  f32x4 acc[4];
  #pragma unroll
  for(int nf=0;nf<4;nf++){ acc[nf][0]=0.f; acc[nf][1]=0.f; acc[nf][2]=0.f; acc[nf][3]=0.f; }
  float m_run = -3e38f, l_run = 0.f;

  // prologue: stage K tile 0 into buf 0
  gld16(kg + (long)strow*64 + scs, &Kl[0][(w*8)*64]);

  for(int t=0; t<6; t++){
    #define ATTN_ITER(u)                                                         \
    {                                                                            \
      const int j = 3*t + (u);                                                   \
      const int cur = (t + (u)) & 1;                                             \
      asm volatile("s_waitcnt vmcnt(0)" ::: "memory");                           \
      __builtin_amdgcn_sched_barrier(0);                                         \
      __builtin_amdgcn_s_barrier();                                              \
      __builtin_amdgcn_sched_barrier(0);                                         \
      /* V fragments direct from global (L2-hot), issued FIRST */                \
      bf16x8 vv[8];                                                              \
      _Pragma("unroll")                                                          \
      for(int nf=0;nf<4;nf++)                                                    \
        _Pragma("unroll")                                                        \
        for(int ks=0;ks<2;ks++)                                                  \
          vv[nf*2+ks] = *(const bf16x8*)(vg + (long)(nf*16+la)*2304 + j*64 + (ks*4+grp)*8); \
      const int h0 = sp*24 + 4*t + (u);                                          \
      const float rha = rhq[h0];                                                 \
      const float rhb = rhq[h0+1];                                               \
      /* K prefetch LAST so it stays outstanding past the pre-PV waitcnt */      \
      if(j+1 < NTS)                                                              \
        gld16(kg + ((long)((j+1)*64 + strow))*64 + scs, &Kl[cur^1][(w*8)*64]);   \
      f32x4 s[4];                                                                \
      _Pragma("unroll")                                                          \
      for(int nf=0;nf<4;nf++){                                                   \
        const ushort_t* kl = &Kl[cur][(nf*16+la)*64];                            \
        bf16x8 k0 = *(const bf16x8*)(kl + ((grp ^ (la&7))*8));                   \
        bf16x8 k1 = *(const bf16x8*)(kl + (((4+grp) ^ (la&7))*8));               \
        f32x4 z; z[0]=0.f; z[1]=0.f; z[2]=0.f; z[3]=0.f;                         \
        z = MFMA16(k0, qa0, z);                                                  \
        z = MFMA16(k1, qa1, z);                                                  \
        s[nf] = z;                                                               \
      }                                                                          \
      float lmax = -3e38f;                                                       \
      _Pragma("unroll")                                                          \
      for(int nf=0;nf<4;nf++){                                                   \
        const int cp = (u) + nf;                                                 \
        const float rh = (cp >= 3) ? rhb : rha;                                  \
        const int c = (cp >= 3) ? cp-3 : cp;                                     \
        _Pragma("unroll")                                                        \
        for(int r=0;r<4;r++){                                                    \
          s[nf][r] += rh + rw4[c][r];                                            \
          lmax = fmaxf(lmax, s[nf][r]);                                          \
        }                                                                        \
      }                                                                          \
      lmax = fmaxf(lmax, __shfl_xor(lmax,16));                                   \
      lmax = fmaxf(lmax, __shfl_xor(lmax,32));                                   \
      if(!__all(lmax <= m_run + 8.f)){                                           \
        const float mnew = fmaxf(m_run, lmax);                                   \
        const float alpha = __expf(m_run - mnew);                                \
        m_run = mnew;                                                            \
        l_run *= alpha;                                                          \
        _Pragma("unroll")                                                        \
        for(int nf=0;nf<4;nf++)                                                  \
          _Pragma("unroll")                                                      \
          for(int r=0;r<4;r++) acc[nf][r] *= alpha;                              \
      }                                                                          \
      float psum = 0.f;                                                          \
      _Pragma("unroll")                                                          \
      for(int nf=0;nf<4;nf++)                                                    \
        _Pragma("unroll")                                                        \
        for(int r=0;r<4;r++){                                                    \
          s[nf][r] = __expf(s[nf][r] - m_run);                                   \
          psum += s[nf][r];                                                      \
        }                                                                        \
      psum += __shfl_xor(psum,16);                                               \
      psum += __shfl_xor(psum,32);                                               \
      l_run += psum;                                                             \
      unsigned pk[4][2];                                                         \
      _Pragma("unroll")                                                          \
      for(int nf=0;nf<4;nf++)                                                    \
        _Pragma("unroll")                                                        \
        for(int h=0;h<2;h++)                                                     \
          asm("v_cvt_pk_bf16_f32 %0, %1, %2"                                     \
              : "=v"(pk[nf][h]) : "v"(s[nf][2*h]), "v"(s[nf][2*h+1]));           \
      _Pragma("unroll")                                                          \
      for(int ks=0; ks<2; ks++){                                                 \
        unsigned wd[4];                                                          \
        _Pragma("unroll")                                                        \
        for(int j2=0;j2<4;j2++){                                                 \
          int src = la + 16*(((grp&1)<<1) + (j2>>1));                            \
          unsigned wA = __shfl(pk[2*ks  ][j2&1], src);                           \
          unsigned wB = __shfl(pk[2*ks+1][j2&1], src);                           \
          wd[j2] = (grp >= 2) ? wB : wA;                                         \
        }                                                                        \
        union { unsigned uu[4]; bf16x8 v; } pa;                                  \
        pa.uu[0]=wd[0]; pa.uu[1]=wd[1]; pa.uu[2]=wd[2]; pa.uu[3]=wd[3];          \
        _Pragma("unroll")                                                        \
        for(int nf=0;nf<4;nf++)                                                  \
          acc[nf] = MFMA16(vv[nf*2+ks], pa.v, acc[nf]);                          \
      }                                                                          \
    }
    ATTN_ITER(0)
    ATTN_ITER(1)
    ATTN_ITER(2)
    #undef ATTN_ITER
  }

  float* op = Opart + ((long)sp*55296 + row)*64;
  #pragma unroll
  for(int nf=0;nf<4;nf++)
    *(f32x4*)(op + nf*16 + grp*4) = acc[nf];
  if(grp == 0){
    mpart[(long)sp*55296 + row] = m_run;
    lpart[(long)sp*55296 + row] = l_run;
  }
}

// merge 2 partials
__global__ __launch_bounds__(256) void attn_merge_kernel(
    const float* __restrict__ Opart, const float* __restrict__ mpart,
    const float* __restrict__ lpart, ushort_t* __restrict__ outp){
  int wid = threadIdx.x >> 6, lane = threadIdx.x & 63;
  long row = (long)blockIdx.x*4 + wid;
  int bh = (int)(row / 2304); int n = (int)(row - (long)bh*2304);
  int b = bh / 12, head = bh - b*12;
  float m0 = mpart[row], m1 = mpart[55296+row];
  float ms = fmaxf(m0, m1);
  float w0 = __expf(m0-ms), w1 = __expf(m1-ms);
  float l = w0*lpart[row] + w1*lpart[55296+row];
  float o = w0*Opart[row*64+lane] + w1*Opart[(55296+row)*64+lane];
  outp[((long)b*2304+n)*768 + head*64 + lane] = f2bf(o / l);
}

// ---------------- launch ----------------
extern "C" void kernel_launch(void* const* d_in, const int* in_sizes, int n_in,
                              void* d_out, int out_size, void* d_ws, size_t ws_size,
                              hipStream_t stream){
  const float* x     = (const float*)d_in[0];
  const float* n1w   = (const float*)d_in[1];
  const float* n1b   = (const float*)d_in[2];
  const float* qkvw  = (const float*)d_in[3];
  const float* qkvb  = (const float*)d_in[4];
  const float* projw = (const float*)d_in[5];
  const float* projb = (const float*)d_in[6];
  const float* rph   = (const float*)d_in[7];
  const float* rpw   = (const float*)d_in[8];
  const float* n2w   = (const float*)d_in[9];
  const float* n2b   = (const float*)d_in[10];
  const float* fc1w  = (const float*)d_in[11];
  const float* fc1b  = (const float*)d_in[12];
  const float* fc2w  = (const float*)d_in[13];
  const float* fc2b  = (const float*)d_in[14];
  const float* c1w   = (const float*)d_in[15];
  const float* r1w   = (const float*)d_in[16];
  const float* r1b   = (const float*)d_in[17];
  const float* c2w   = (const float*)d_in[18];
  const float* r2w   = (const float*)d_in[19];
  const float* r2b   = (const float*)d_in[20];
  const float* c3w   = (const float*)d_in[21];
  const float* r3w   = (const float*)d_in[22];
  const float* r3b   = (const float*)d_in[23];
  float* out = (float*)d_out;

  char* base = (char*)d_ws;
  size_t off = 0;
  auto carve = [&](size_t bytes)->char*{
    char* p = base + off;
    off += (bytes + 255) & ~(size_t)255;
    return p;
  };
  const long T = 4608;

  ushort_t* wqkvT = (ushort_t*)carve((size_t)2304*768*2);
  ushort_t* wprojT= (ushort_t*)carve((size_t)768*768*2);
  ushort_t* wfc1T = (ushort_t*)carve((size_t)3072*768*2);
  ushort_t* wfc2T = (ushort_t*)carve((size_t)768*3072*2);
  ushort_t* wc1   = (ushort_t*)carve((size_t)384*768*2);
  ushort_t* wc2   = (ushort_t*)carve((size_t)384*3456*2);
  ushort_t* wc3   = (ushort_t*)carve((size_t)768*384*2);
  ushort_t* tabhb = (ushort_t*)carve((size_t)95*64*2);
  ushort_t* tabwb = (ushort_t*)carve((size_t)95*64*2);
  ushort_t* xn1   = (ushort_t*)carve((size_t)T*768*2);
  ushort_t* qb    = (ushort_t*)carve((size_t)24*2304*64*2);
  ushort_t* kbuf  = (ushort_t*)carve((size_t)24*2304*64*2);
  ushort_t* vbuf  = (ushort_t*)carve((size_t)24*2304*64*2);
  ushort_t* vbufT = (ushort_t*)carve((size_t)24*2304*64*2);
  float*    relh  = (float*)carve((size_t)24*2304*48*4);
  float*    relw  = (float*)carve((size_t)24*2304*48*4);
  float*    Opart = (float*)carve((size_t)2*55296*64*4);
  float*    mpart = (float*)carve((size_t)2*55296*4);
  float*    lpart = (float*)carve((size_t)2*55296*4);
  ushort_t* attno = (ushort_t*)carve((size_t)T*768*2);
  float*    x1    = (float*)carve((size_t)T*768*4);
  ushort_t* xn2   = (ushort_t*)carve((size_t)T*768*2);
  ushort_t* hmlp  = (ushort_t*)carve((size_t)T*3072*2);
  float*    x2    = (float*)carve((size_t)T*768*4);
  ushort_t* x2b   = (ushort_t*)carve((size_t)T*768*2);
  float*    c1    = (float*)carve((size_t)T*384*4);
  ushort_t* o1pad = (ushort_t*)carve((size_t)2*50*50*384*2);
  float*    c2    = (float*)carve((size_t)T*384*4);
  ushort_t* o2    = (ushort_t*)carve((size_t)T*384*2);
  float*    c3    = (float*)carve((size_t)T*768*4);
  (void)ws_size; (void)in_sizes; (void)n_in; (void)out_size;

  // fused weight prep
  transpose_all_kernel<<<dim3(6912),256,0,stream>>>(qkvw, projw, fc1w, fc2w,
                                                    wqkvT, wprojT, wfc1T, wfc2T);
  cast_all_kernel<<<dim3(7536),256,0,stream>>>(c1w, c2w, c3w, rph, rpw,
                                               wc1, wc2, wc3, tabhb, tabwb);
  hipMemsetAsync(o1pad, 0, (size_t)2*50*50*384*2, stream);

  // LN1
  ln_kernel<768,false,false,false><<<dim3(1152),256,0,stream>>>(x, n1w, n1b, nullptr, 1e-5f, xn1, nullptr);
  // QKV + scatter (q scaled by 0.125)
  gemm_kernel<128,128,1,false><<<dim3(18,36),256,0,stream>>>(xn1, wqkvT, qkvb, nullptr, nullptr, qb, kbuf, vbuf, 2304, 768);
  // V transpose
  vt_kernel<<<dim3(36,24),256,0,stream>>>(vbuf, vbufT);
  // rel-pos bias tables (MFMA)
  relpos_mfma_kernel<<<dim3(12,24,2),256,0,stream>>>(qb, tabhb, tabwb, relh, relw);
  // flash attention (split-KV x2, 8 waves x 16q, V from L2) + merge
  attn_kernel<<<dim3(18,24,2),512,0,stream>>>(qb, kbuf, vbufT, relh, relw, Opart, mpart, lpart);
  attn_merge_kernel<<<dim3(13824),256,0,stream>>>(Opart, mpart, lpart, attno);
  // proj + residual(x)
  gemm_kernel<64,64,2,false><<<dim3(12,72),256,0,stream>>>(attno, wprojT, projb, x, x1, nullptr, nullptr, nullptr, 768, 768);
  // LN2
  ln_kernel<768,false,false,false><<<dim3(1152),256,0,stream>>>(x1, n2w, n2b, nullptr, 1e-5f, xn2, nullptr);
  // fc1 + GELU
  gemm_kernel<128,128,3,false><<<dim3(24,36),256,0,stream>>>(xn2, wfc1T, fc1b, nullptr, nullptr, hmlp, nullptr, nullptr, 3072, 768);
  // fc2 + residual(x1) -> x2 (f32+bf16), 128x64 tile (K=3072 amortizes staging)
  gemm_kernel<128,64,4,false><<<dim3(12,36),256,0,stream>>>(hmlp, wfc2T, fc2b, x1, x2, x2b, nullptr, nullptr, 768, 3072);
  // conv1 (1x1)
  gemm_kernel<64,64,0,false><<<dim3(6,72),256,0,stream>>>(x2b, wc1, nullptr, nullptr, c1, nullptr, nullptr, nullptr, 384, 768);
  ln_kernel<384,true,false,true><<<dim3(1152),256,0,stream>>>(c1, r1w, r1b, nullptr, 1e-6f, o1pad, nullptr);
  // conv2 (3x3 via padded im2col)
  gemm_kernel<64,64,0,true><<<dim3(6,72),256,0,stream>>>(o1pad, wc2, nullptr, nullptr, c2, nullptr, nullptr, nullptr, 384, 3456);
  ln_kernel<384,true,false,false><<<dim3(1152),256,0,stream>>>(c2, r2w, r2b, nullptr, 1e-6f, o2, nullptr);
  // conv3 (1x1)
  gemm_kernel<64,64,0,false><<<dim3(12,72),256,0,stream>>>(o2, wc3, nullptr, nullptr, c3, nullptr, nullptr, nullptr, 768, 384);
  // final chan-LN + residual(x2) -> out
  ln_kernel<768,false,true,false><<<dim3(1152),256,0,stream>>>(c3, r3w, r3b, x2, 1e-6f, nullptr, out);
}

// Round 11
// 423.004 us; speedup vs baseline: 1.2395x; 1.2395x over previous
//
#include <hip/hip_runtime.h>

typedef unsigned short ushort_t;
typedef __attribute__((ext_vector_type(8))) short bf16x8;
typedef __attribute__((ext_vector_type(4))) float f32x4;

#define DEV static __device__ __forceinline__

DEV ushort_t f2bf(float f){
  union { float f; unsigned u; } v; v.f = f;
  unsigned r = v.u + 0x7FFFu + ((v.u >> 16) & 1u);
  return (ushort_t)(r >> 16);
}
DEV float bf2f(ushort_t h){
  union { unsigned u; float f; } v; v.u = ((unsigned)h) << 16;
  return v.f;
}
DEV float gelu_f(float x){ return 0.5f * x * (1.f + erff(x * 0.70710678118654752f)); }

#define MFMA16(a,b,c) __builtin_amdgcn_mfma_f32_16x16x32_bf16((a),(b),(c),0,0,0)

DEV void gld16(const ushort_t* g, ushort_t* l){
  __builtin_amdgcn_global_load_lds(
      (const __attribute__((address_space(1))) unsigned int*)g,
      (__attribute__((address_space(3))) unsigned int*)l, 16, 0, 0);
}

// ---------------- fused weight prep ----------------

__global__ __launch_bounds__(256) void transpose_all_kernel(
    const float* __restrict__ s0, const float* __restrict__ s1,
    const float* __restrict__ s2, const float* __restrict__ s3,
    ushort_t* __restrict__ d0, ushort_t* __restrict__ d1,
    ushort_t* __restrict__ d2, ushort_t* __restrict__ d3){
  __shared__ float tile[32][33];
  int b = blockIdx.x;
  const float* src; ushort_t* dst; int K, N, bx, by;
  if(b < 1728){ src=s0; dst=d0; K=768;  N=2304; bx=b%24;          by=b/24; }
  else if(b < 2304){ int c=b-1728; src=s1; dst=d1; K=768;  N=768;  bx=c%24; by=c/24; }
  else if(b < 4608){ int c=b-2304; src=s2; dst=d2; K=768;  N=3072; bx=c%24; by=c/24; }
  else             { int c=b-4608; src=s3; dst=d3; K=3072; N=768;  bx=c%96; by=c/96; }
  int k0 = bx*32, n0 = by*32;
  int tx = threadIdx.x & 31, ty = threadIdx.x >> 5;
  #pragma unroll
  for(int i = ty; i < 32; i += 8) tile[i][tx] = src[(long)(k0+i)*N + n0 + tx];
  __syncthreads();
  #pragma unroll
  for(int i = ty; i < 32; i += 8) dst[(long)(n0+i)*K + k0 + tx] = f2bf(tile[tx][i]);
}

__global__ void cast_all_kernel(
    const float* __restrict__ c1w, const float* __restrict__ c2w,
    const float* __restrict__ c3w, const float* __restrict__ rph,
    const float* __restrict__ rpw,
    ushort_t* __restrict__ wc1, ushort_t* __restrict__ wc2,
    ushort_t* __restrict__ wc3, ushort_t* __restrict__ tabh,
    ushort_t* __restrict__ tabw){
  int i = blockIdx.x*256 + threadIdx.x;
  if(i < 294912){ wc1[i] = f2bf(c1w[i]); }
  else if(i < 1622016){
    int j = i - 294912;
    int co = j / 3456, r = j - co*3456;
    int dy = r / 1152; int r2 = r - dy*1152;
    int dx = r2 / 384; int ci = r2 - dx*384;
    wc2[j] = f2bf(c2w[((co*384 + ci)*3 + dy)*3 + dx]);
  }
  else if(i < 1916928){ int j = i - 1622016; wc3[j] = f2bf(c3w[j]); }
  else if(i < 1923008){ int j = i - 1916928; tabh[j] = f2bf(rph[j]); }
  else if(i < 1929088){ int j = i - 1923008; tabw[j] = f2bf(rpw[j]); }
}

// V [bh][n][64] -> VT [bh][64][n]
__global__ __launch_bounds__(256) void vt_kernel(
    const ushort_t* __restrict__ v, ushort_t* __restrict__ vt){
  __shared__ __align__(16) ushort_t t[64][72];
  int bh = blockIdx.y, nt = blockIdx.x;
  int tid = threadIdx.x;
  #pragma unroll
  for(int p=0;p<2;p++){
    int item = tid + p*256;
    int tok = item >> 3, ch = item & 7;
    bf16x8 vv = *(const bf16x8*)(v + ((long)(bh*2304 + nt*64 + tok))*64 + ch*8);
    #pragma unroll
    for(int j=0;j<8;j++) t[ch*8+j][tok] = (ushort_t)vv[j];
  }
  __syncthreads();
  #pragma unroll
  for(int p=0;p<2;p++){
    int item = tid + p*256;
    int d = item >> 3, c2 = item & 7;
    bf16x8 rd = *(const bf16x8*)&t[d][c2*8];
    *(bf16x8*)(vt + ((long)(bh*64 + d))*2304 + nt*64 + c2*8) = rd;
  }
}

// ---------------- LayerNorm ----------------
template<int D, bool GELU, bool RES, bool PADOUT>
__global__ __launch_bounds__(256) void ln_kernel(
    const float* __restrict__ in, const float* __restrict__ w, const float* __restrict__ bv,
    const float* __restrict__ res, float eps,
    ushort_t* __restrict__ outb, float* __restrict__ outf){
  constexpr int PER = D/64;
  int lane = threadIdx.x & 63, wid = threadIdx.x >> 6;
  long row = (long)blockIdx.x*4 + wid;
  const float* ip = in + row*D;
  float x[PER]; float s = 0.f;
  #pragma unroll
  for(int i=0;i<PER;i++){ x[i] = ip[i*64 + lane]; s += x[i]; }
  #pragma unroll
  for(int o=32;o>=1;o>>=1) s += __shfl_xor(s, o);
  float mu = s * (1.f/D);
  float vs = 0.f;
  #pragma unroll
  for(int i=0;i<PER;i++){ float d = x[i]-mu; vs += d*d; }
  #pragma unroll
  for(int o=32;o>=1;o>>=1) vs += __shfl_xor(vs, o);
  float rstd = rsqrtf(vs*(1.f/D) + eps);
  long obase;
  if constexpr(PADOUT){
    int bb = (int)(row / 2304); int rm = (int)(row - (long)bb*2304);
    int y = rm / 48, xx = rm - y*48;
    obase = ((long)((bb*50 + y+1)*50) + (xx+1))*384;
  } else obase = row*D;
  #pragma unroll
  for(int i=0;i<PER;i++){
    int c = i*64 + lane;
    float y = (x[i]-mu)*rstd*w[c] + bv[c];
    if constexpr(GELU) y = gelu_f(y);
    if constexpr(RES)  y += res[row*D + c];
    if(outb) outb[obase + c] = f2bf(y);
    if(outf) outf[row*D + c] = y;
  }
}

// ---------------- rel-pos bias tables via MFMA ----------------
__global__ __launch_bounds__(256) void relpos_mfma_kernel(
    const ushort_t* __restrict__ q, const ushort_t* __restrict__ tabh,
    const ushort_t* __restrict__ tabw,
    float* __restrict__ relh, float* __restrict__ relw){
  const int bh = blockIdx.y;
  const bool isH = (blockIdx.z == 0);
  const int w = threadIdx.x >> 6, lane = threadIdx.x & 63;
  const int la = lane & 15, grp = lane >> 4;
  const int pos0 = blockIdx.x*4 + w;
  const ushort_t* tab = isH ? tabh : tabw;
  float* outp = isH ? relh : relw;
  const ushort_t* qbase = q + (long)bh*2304*64;

  bf16x8 bf0[3], bf1[3];
  #pragma unroll
  for(int ni=0;ni<3;ni++){
    int dpos = pos0 - (ni*16+la) + 47;
    const ushort_t* tp = tab + dpos*64 + grp*8;
    bf0[ni] = *(const bf16x8*)tp;
    bf1[ni] = *(const bf16x8*)(tp+32);
  }
  #pragma unroll
  for(int mi=0;mi<3;mi++){
    int arow = mi*16 + la;
    long na = isH ? ((long)pos0*48 + arow) : ((long)arow*48 + pos0);
    const ushort_t* qp = qbase + na*64 + grp*8;
    bf16x8 a0 = *(const bf16x8*)qp;
    bf16x8 a1 = *(const bf16x8*)(qp+32);
    f32x4 c[3];
    #pragma unroll
    for(int ni=0;ni<3;ni++){
      f32x4 z; z[0]=0.f; z[1]=0.f; z[2]=0.f; z[3]=0.f;
      z = MFMA16(a0, bf0[ni], z);
      z = MFMA16(a1, bf1[ni], z);
      c[ni] = z;
    }
    #pragma unroll
    for(int ni=0;ni<3;ni++)
      #pragma unroll
      for(int r=0;r<4;r++){
        int orow = mi*16 + grp*4 + r;
        long no = isH ? ((long)pos0*48 + orow) : ((long)orow*48 + pos0);
        outp[((long)bh*2304 + no)*48 + ni*16 + la] = c[ni][r] * 8.0f;
      }
  }
}

// ---------------- MFMA GEMM, BM x BN tile, gld16 + XOR-swizzle ----------------
template<int BM, int BN, int EPI, bool IM2COL>
__global__ __launch_bounds__(256) void gemm_kernel(
    const ushort_t* __restrict__ A, const ushort_t* __restrict__ Wt,
    const float* __restrict__ bias, const float* __restrict__ res,
    float* __restrict__ outf, ushort_t* __restrict__ ob0,
    ushort_t* __restrict__ ob1, ushort_t* __restrict__ ob2,
    int N, int Kdim){
  constexpr int FRm = BM/32, FRn = BN/32;
  __shared__ __align__(16) ushort_t Asm[BM*64];
  __shared__ __align__(16) ushort_t Bsm[BN*64];
  const int tid = threadIdx.x, lane = tid & 63, w = tid >> 6;
  const int wm = w >> 1, wn = w & 1;
  const int la = lane & 15, grp = lane >> 4;
  const int m0 = blockIdx.y * BM, n0 = blockIdx.x * BN;
  f32x4 acc[FRm][FRn];
  #pragma unroll
  for(int i=0;i<FRm;i++)
    #pragma unroll
    for(int j=0;j<FRn;j++)
      #pragma unroll
      for(int r=0;r<4;r++) acc[i][j][r] = 0.f;

  const int srw = lane >> 3;
  const int scs = ((lane&7) ^ srw) * 8;
  for(int k0 = 0; k0 < Kdim; k0 += 64){
    if(k0) __syncthreads();
    #pragma unroll
    for(int t=0;t<FRm;t++){
      int r = w*(BM/4) + t*8 + srw;
      const ushort_t* ga;
      if constexpr(IM2COL){
        int m = m0 + r;
        int bb = m / 2304; int rm = m - bb*2304;
        int y = rm / 48, x = rm - y*48;
        int dy = k0 / 1152; int r2 = k0 - dy*1152;
        int dx = r2 / 384;  int cb = r2 - dx*384;
        ga = A + (((long)((bb*50 + y+dy)*50) + (x+dx))*384 + cb + scs);
      } else {
        ga = A + (long)(m0+r)*Kdim + k0 + scs;
      }
      gld16(ga, &Asm[(w*(BM/4)+t*8)*64]);
    }
    #pragma unroll
    for(int t=0;t<FRn;t++){
      int r = w*(BN/4) + t*8 + srw;
      gld16(Wt + (long)(n0+r)*Kdim + k0 + scs, &Bsm[(w*(BN/4)+t*8)*64]);
    }
    __syncthreads();
    #pragma unroll
    for(int ks=0; ks<2; ks++){
      bf16x8 af[FRm], bfm[FRn];
      #pragma unroll
      for(int mi=0;mi<FRm;mi++){
        int row = wm*(BM/2) + mi*16 + la;
        af[mi] = *(const bf16x8*)&Asm[row*64 + ((((ks<<2)+grp) ^ (row&7))*8)];
      }
      #pragma unroll
      for(int ni=0;ni<FRn;ni++){
        int row = wn*(BN/2) + ni*16 + la;
        bfm[ni] = *(const bf16x8*)&Bsm[row*64 + ((((ks<<2)+grp) ^ (row&7))*8)];
      }
      #pragma unroll
      for(int mi=0;mi<FRm;mi++)
        #pragma unroll
        for(int ni=0;ni<FRn;ni++)
          acc[mi][ni] = MFMA16(af[mi], bfm[ni], acc[mi][ni]);
    }
  }
  #pragma unroll
  for(int mi=0;mi<FRm;mi++)
  #pragma unroll
  for(int ni=0;ni<FRn;ni++)
  #pragma unroll
  for(int r=0;r<4;r++){
    int mm = m0 + wm*(BM/2) + mi*16 + grp*4 + r;
    int nn = n0 + wn*(BN/2) + ni*16 + la;
    float v = acc[mi][ni][r];
    if constexpr(EPI == 0){
      outf[(long)mm*N + nn] = v;
    } else if constexpr(EPI == 1){
      v += bias[nn];
      int s = nn / 768; int rem = nn - s*768;
      int head = rem >> 6, d = rem & 63;
      if(s == 0) v *= 0.125f;
      int bb = mm / 2304; int nloc = mm - bb*2304;
      long idx = ((long)((bb*12+head)*2304 + nloc))*64 + d;
      ushort_t hv = f2bf(v);
      if(s == 0) ob0[idx] = hv; else if(s == 1) ob1[idx] = hv; else ob2[idx] = hv;
    } else if constexpr(EPI == 2){
      v += bias[nn] + res[(long)mm*N + nn];
      outf[(long)mm*N + nn] = v;
    } else if constexpr(EPI == 3){
      v = gelu_f(v + bias[nn]);
      ob0[(long)mm*N + nn] = f2bf(v);
    } else if constexpr(EPI == 4){
      v += bias[nn] + res[(long)mm*N + nn];
      outf[(long)mm*N + nn] = v;
      ob0[(long)mm*N + nn] = f2bf(v);
    }
  }
}

// ---------------- flash attention: 8 waves x 16q, K+V LDS 2-phase pipeline, split-KV (r8) ----------------
#define NSPLIT 2
#define NTS 18
__global__ __launch_bounds__(512) void attn_kernel(
    const ushort_t* __restrict__ Q, const ushort_t* __restrict__ Kb,
    const ushort_t* __restrict__ VT, const float* __restrict__ relh,
    const float* __restrict__ relw, float* __restrict__ Opart,
    float* __restrict__ mpart, float* __restrict__ lpart){
  __shared__ __align__(16) ushort_t Kl[2][64*64];
  __shared__ __align__(16) ushort_t Vl[2][64*64];
  const int bh = blockIdx.y, qt = blockIdx.x, sp = blockIdx.z;
  const int tid = threadIdx.x, lane = tid & 63, w = tid >> 6;   // w 0..7
  const int la = lane & 15, grp = lane >> 4;
  const int qg = qt*128 + w*16 + la;
  const long row = (long)bh*2304 + qg;
  const int key0 = sp*NTS*64;

  const ushort_t* qp = Q + row*64 + grp*8;
  const bf16x8 qa0 = *(const bf16x8*)qp;
  const bf16x8 qa1 = *(const bf16x8*)(qp + 32);

  const ushort_t* kg = Kb + ((long)bh*2304 + key0)*64;
  const ushort_t* vg = VT + (long)bh*64*2304 + key0;
  const float* rhq = relh + row*48;

  f32x4 rw4[3];
  {
    const float* rwq = relw + row*48 + grp*4;
    #pragma unroll
    for(int c=0;c<3;c++) rw4[c] = *(const f32x4*)(rwq + 16*c);
  }

  const int srw = lane >> 3;
  const int scs = ((lane&7) ^ srw) * 8;
  const int strow = w*8 + srw;

  f32x4 acc[4];
  #pragma unroll
  for(int nf=0;nf<4;nf++){ acc[nf][0]=0.f; acc[nf][1]=0.f; acc[nf][2]=0.f; acc[nf][3]=0.f; }
  float m_run = -3e38f, l_run = 0.f;

  gld16(kg + (long)strow*64 + scs, &Kl[0][(w*8)*64]);
  gld16(vg + (long)strow*2304 + scs, &Vl[0][(w*8)*64]);

  for(int t=0; t<6; t++){
    #define ATTN_ITER(u)                                                         \
    {                                                                            \
      const int j = 3*t + (u);                                                   \
      const int cur = (t + (u)) & 1;                                             \
      asm volatile("s_waitcnt vmcnt(0)" ::: "memory");                           \
      __builtin_amdgcn_sched_barrier(0);                                         \
      __builtin_amdgcn_s_barrier();                                              \
      __builtin_amdgcn_sched_barrier(0);                                         \
      const int h0 = sp*24 + 4*t + (u);                                          \
      const float rha = rhq[h0];                                                 \
      const float rhb = rhq[h0+1];                                               \
      if(j+1 < NTS){                                                             \
        gld16(kg + ((long)((j+1)*64 + strow))*64 + scs, &Kl[cur^1][(w*8)*64]);   \
        gld16(vg + (long)strow*2304 + (j+1)*64 + scs, &Vl[cur^1][(w*8)*64]);     \
      }                                                                          \
      f32x4 s[4];                                                                \
      _Pragma("unroll")                                                          \
      for(int nf=0;nf<4;nf++){                                                   \
        const ushort_t* kl = &Kl[cur][(nf*16+la)*64];                            \
        bf16x8 k0 = *(const bf16x8*)(kl + ((grp ^ (la&7))*8));                   \
        bf16x8 k1 = *(const bf16x8*)(kl + (((4+grp) ^ (la&7))*8));               \
        f32x4 z; z[0]=0.f; z[1]=0.f; z[2]=0.f; z[3]=0.f;                         \
        z = MFMA16(k0, qa0, z);                                                  \
        z = MFMA16(k1, qa1, z);                                                  \
        s[nf] = z;                                                               \
      }                                                                          \
      float lmax = -3e38f;                                                       \
      _Pragma("unroll")                                                          \
      for(int nf=0;nf<4;nf++){                                                   \
        const int cp = (u) + nf;                                                 \
        const float rh = (cp >= 3) ? rhb : rha;                                  \
        const int c = (cp >= 3) ? cp-3 : cp;                                     \
        _Pragma("unroll")                                                        \
        for(int r=0;r<4;r++){                                                    \
          s[nf][r] += rh + rw4[c][r];                                            \
          lmax = fmaxf(lmax, s[nf][r]);                                          \
        }                                                                        \
      }                                                                          \
      lmax = fmaxf(lmax, __shfl_xor(lmax,16));                                   \
      lmax = fmaxf(lmax, __shfl_xor(lmax,32));                                   \
      if(!__all(lmax <= m_run + 8.f)){                                           \
        const float mnew = fmaxf(m_run, lmax);                                   \
        const float alpha = __expf(m_run - mnew);                                \
        m_run = mnew;                                                            \
        l_run *= alpha;                                                          \
        _Pragma("unroll")                                                        \
        for(int nf=0;nf<4;nf++)                                                  \
          _Pragma("unroll")                                                      \
          for(int r=0;r<4;r++) acc[nf][r] *= alpha;                              \
      }                                                                          \
      float psum = 0.f;                                                          \
      _Pragma("unroll")                                                          \
      for(int nf=0;nf<4;nf++)                                                    \
        _Pragma("unroll")                                                        \
        for(int r=0;r<4;r++){                                                    \
          s[nf][r] = __expf(s[nf][r] - m_run);                                   \
          psum += s[nf][r];                                                      \
        }                                                                        \
      psum += __shfl_xor(psum,16);                                               \
      psum += __shfl_xor(psum,32);                                               \
      l_run += psum;                                                             \
      unsigned pk[4][2];                                                         \
      _Pragma("unroll")                                                          \
      for(int nf=0;nf<4;nf++)                                                    \
        _Pragma("unroll")                                                        \
        for(int h=0;h<2;h++)                                                     \
          asm("v_cvt_pk_bf16_f32 %0, %1, %2"                                     \
              : "=v"(pk[nf][h]) : "v"(s[nf][2*h]), "v"(s[nf][2*h+1]));           \
      _Pragma("unroll")                                                          \
      for(int ks=0; ks<2; ks++){                                                 \
        unsigned wd[4];                                                          \
        _Pragma("unroll")                                                        \
        for(int j2=0;j2<4;j2++){                                                 \
          int src = la + 16*(((grp&1)<<1) + (j2>>1));                            \
          unsigned wA = __shfl(pk[2*ks  ][j2&1], src);                           \
          unsigned wB = __shfl(pk[2*ks+1][j2&1], src);                           \
          wd[j2] = (grp >= 2) ? wB : wA;                                         \
        }                                                                        \
        union { unsigned uu[4]; bf16x8 v; } pa;                                  \
        pa.uu[0]=wd[0]; pa.uu[1]=wd[1]; pa.uu[2]=wd[2]; pa.uu[3]=wd[3];          \
        _Pragma("unroll")                                                        \
        for(int nf=0;nf<4;nf++){                                                 \
          const ushort_t* vl = &Vl[cur][(nf*16+la)*64];                          \
          bf16x8 vb = *(const bf16x8*)(vl + ((((ks<<2)+grp) ^ (la&7))*8));       \
          acc[nf] = MFMA16(vb, pa.v, acc[nf]);                                   \
        }                                                                        \
      }                                                                          \
    }
    ATTN_ITER(0)
    ATTN_ITER(1)
    ATTN_ITER(2)
    #undef ATTN_ITER
  }

  float* op = Opart + ((long)sp*55296 + row)*64;
  #pragma unroll
  for(int nf=0;nf<4;nf++)
    *(f32x4*)(op + nf*16 + grp*4) = acc[nf];
  if(grp == 0){
    mpart[(long)sp*55296 + row] = m_run;
    lpart[(long)sp*55296 + row] = l_run;
  }
}

// merge 2 partials
__global__ __launch_bounds__(256) void attn_merge_kernel(
    const float* __restrict__ Opart, const float* __restrict__ mpart,
    const float* __restrict__ lpart, ushort_t* __restrict__ outp){
  int wid = threadIdx.x >> 6, lane = threadIdx.x & 63;
  long row = (long)blockIdx.x*4 + wid;
  int bh = (int)(row / 2304); int n = (int)(row - (long)bh*2304);
  int b = bh / 12, head = bh - b*12;
  float m0 = mpart[row], m1 = mpart[55296+row];
  float ms = fmaxf(m0, m1);
  float w0 = __expf(m0-ms), w1 = __expf(m1-ms);
  float l = w0*lpart[row] + w1*lpart[55296+row];
  float o = w0*Opart[row*64+lane] + w1*Opart[(55296+row)*64+lane];
  outp[((long)b*2304+n)*768 + head*64 + lane] = f2bf(o / l);
}

// ---------------- launch ----------------
extern "C" void kernel_launch(void* const* d_in, const int* in_sizes, int n_in,
                              void* d_out, int out_size, void* d_ws, size_t ws_size,
                              hipStream_t stream){
  const float* x     = (const float*)d_in[0];
  const float* n1w   = (const float*)d_in[1];
  const float* n1b   = (const float*)d_in[2];
  const float* qkvw  = (const float*)d_in[3];
  const float* qkvb  = (const float*)d_in[4];
  const float* projw = (const float*)d_in[5];
  const float* projb = (const float*)d_in[6];
  const float* rph   = (const float*)d_in[7];
  const float* rpw   = (const float*)d_in[8];
  const float* n2w   = (const float*)d_in[9];
  const float* n2b   = (const float*)d_in[10];
  const float* fc1w  = (const float*)d_in[11];
  const float* fc1b  = (const float*)d_in[12];
  const float* fc2w  = (const float*)d_in[13];
  const float* fc2b  = (const float*)d_in[14];
  const float* c1w   = (const float*)d_in[15];
  const float* r1w   = (const float*)d_in[16];
  const float* r1b   = (const float*)d_in[17];
  const float* c2w   = (const float*)d_in[18];
  const float* r2w   = (const float*)d_in[19];
  const float* r2b   = (const float*)d_in[20];
  const float* c3w   = (const float*)d_in[21];
  const float* r3w   = (const float*)d_in[22];
  const float* r3b   = (const float*)d_in[23];
  float* out = (float*)d_out;

  char* base = (char*)d_ws;
  size_t off = 0;
  auto carve = [&](size_t bytes)->char*{
    char* p = base + off;
    off += (bytes + 255) & ~(size_t)255;
    return p;
  };
  const long T = 4608;

  ushort_t* wqkvT = (ushort_t*)carve((size_t)2304*768*2);
  ushort_t* wprojT= (ushort_t*)carve((size_t)768*768*2);
  ushort_t* wfc1T = (ushort_t*)carve((size_t)3072*768*2);
  ushort_t* wfc2T = (ushort_t*)carve((size_t)768*3072*2);
  ushort_t* wc1   = (ushort_t*)carve((size_t)384*768*2);
  ushort_t* wc2   = (ushort_t*)carve((size_t)384*3456*2);
  ushort_t* wc3   = (ushort_t*)carve((size_t)768*384*2);
  ushort_t* tabhb = (ushort_t*)carve((size_t)95*64*2);
  ushort_t* tabwb = (ushort_t*)carve((size_t)95*64*2);
  ushort_t* xn1   = (ushort_t*)carve((size_t)T*768*2);
  ushort_t* qb    = (ushort_t*)carve((size_t)24*2304*64*2);
  ushort_t* kbuf  = (ushort_t*)carve((size_t)24*2304*64*2);
  ushort_t* vbuf  = (ushort_t*)carve((size_t)24*2304*64*2);
  ushort_t* vbufT = (ushort_t*)carve((size_t)24*2304*64*2);
  float*    relh  = (float*)carve((size_t)24*2304*48*4);
  float*    relw  = (float*)carve((size_t)24*2304*48*4);
  float*    Opart = (float*)carve((size_t)2*55296*64*4);
  float*    mpart = (float*)carve((size_t)2*55296*4);
  float*    lpart = (float*)carve((size_t)2*55296*4);
  ushort_t* attno = (ushort_t*)carve((size_t)T*768*2);
  float*    x1    = (float*)carve((size_t)T*768*4);
  ushort_t* xn2   = (ushort_t*)carve((size_t)T*768*2);
  ushort_t* hmlp  = (ushort_t*)carve((size_t)T*3072*2);
  float*    x2    = (float*)carve((size_t)T*768*4);
  ushort_t* x2b   = (ushort_t*)carve((size_t)T*768*2);
  float*    c1    = (float*)carve((size_t)T*384*4);
  ushort_t* o1pad = (ushort_t*)carve((size_t)2*50*50*384*2);
  float*    c2    = (float*)carve((size_t)T*384*4);
  ushort_t* o2    = (ushort_t*)carve((size_t)T*384*2);
  float*    c3    = (float*)carve((size_t)T*768*4);
  (void)ws_size; (void)in_sizes; (void)n_in; (void)out_size;

  // fused weight prep
  transpose_all_kernel<<<dim3(6912),256,0,stream>>>(qkvw, projw, fc1w, fc2w,
                                                    wqkvT, wprojT, wfc1T, wfc2T);
  cast_all_kernel<<<dim3(7536),256,0,stream>>>(c1w, c2w, c3w, rph, rpw,
                                               wc1, wc2, wc3, tabhb, tabwb);
  hipMemsetAsync(o1pad, 0, (size_t)2*50*50*384*2, stream);

  // LN1
  ln_kernel<768,false,false,false><<<dim3(1152),256,0,stream>>>(x, n1w, n1b, nullptr, 1e-5f, xn1, nullptr);
  // QKV + scatter (q scaled by 0.125)
  gemm_kernel<128,128,1,false><<<dim3(18,36),256,0,stream>>>(xn1, wqkvT, qkvb, nullptr, nullptr, qb, kbuf, vbuf, 2304, 768);
  // V transpose
  vt_kernel<<<dim3(36,24),256,0,stream>>>(vbuf, vbufT);
  // rel-pos bias tables (MFMA)
  relpos_mfma_kernel<<<dim3(12,24,2),256,0,stream>>>(qb, tabhb, tabwb, relh, relw);
  // flash attention (split-KV x2, 8 waves x 16q, K+V in LDS) + merge
  attn_kernel<<<dim3(18,24,2),512,0,stream>>>(qb, kbuf, vbufT, relh, relw, Opart, mpart, lpart);
  attn_merge_kernel<<<dim3(13824),256,0,stream>>>(Opart, mpart, lpart, attno);
  // proj + residual(x) — 128x64 tile, 432 blocks
  gemm_kernel<128,64,2,false><<<dim3(12,36),256,0,stream>>>(attno, wprojT, projb, x, x1, nullptr, nullptr, nullptr, 768, 768);
  // LN2
  ln_kernel<768,false,false,false><<<dim3(1152),256,0,stream>>>(x1, n2w, n2b, nullptr, 1e-5f, xn2, nullptr);
  // fc1 + GELU
  gemm_kernel<128,128,3,false><<<dim3(24,36),256,0,stream>>>(xn2, wfc1T, fc1b, nullptr, nullptr, hmlp, nullptr, nullptr, 3072, 768);
  // fc2 + residual(x1) -> x2 (f32+bf16), 128x64 tile (K=3072 amortizes staging)
  gemm_kernel<128,64,4,false><<<dim3(12,36),256,0,stream>>>(hmlp, wfc2T, fc2b, x1, x2, x2b, nullptr, nullptr, 768, 3072);
  // conv1 (1x1)
  gemm_kernel<64,64,0,false><<<dim3(6,72),256,0,stream>>>(x2b, wc1, nullptr, nullptr, c1, nullptr, nullptr, nullptr, 384, 768);
  ln_kernel<384,true,false,true><<<dim3(1152),256,0,stream>>>(c1, r1w, r1b, nullptr, 1e-6f, o1pad, nullptr);
  // conv2 (3x3 via padded im2col)
  gemm_kernel<64,64,0,true><<<dim3(6,72),256,0,stream>>>(o1pad, wc2, nullptr, nullptr, c2, nullptr, nullptr, nullptr, 384, 3456);
  ln_kernel<384,true,false,false><<<dim3(1152),256,0,stream>>>(c2, r2w, r2b, nullptr, 1e-6f, o2, nullptr);
  // conv3 (1x1) — 128x64 tile, 432 blocks
  gemm_kernel<128,64,0,false><<<dim3(12,36),256,0,stream>>>(o2, wc3, nullptr, nullptr, c3, nullptr, nullptr, nullptr, 768, 384);
  // final chan-LN + residual(x2) -> out
  ln_kernel<768,false,true,false><<<dim3(1152),256,0,stream>>>(c3, r3w, r3b, x2, 1e-6f, nullptr, out);
}